// Round 6
// baseline (89.560 us; speedup 1.0000x reference)
//
#include <hip/hip_runtime.h>

#define B_ 8
#define T_ 2048
#define C_ 1024
#define H_ 64
#define BT_ (B_ * T_)

typedef float f32x4 __attribute__((ext_vector_type(4)));
typedef unsigned short u16x4 __attribute__((ext_vector_type(4)));
typedef unsigned short u16x8 __attribute__((ext_vector_type(8)));
typedef __bf16 bf16x8 __attribute__((ext_vector_type(8)));

// f32 -> bf16 round-to-nearest-even
static __device__ __forceinline__ unsigned short f2bf(float f) {
    unsigned int u = __builtin_bit_cast(unsigned int, f);
    u = (u + 0x7FFFu + ((u >> 16) & 1u)) >> 16;
    return (unsigned short)u;
}

static __device__ __forceinline__ f32x4 mfma16(u16x8 a, u16x8 b, f32x4 c) {
    return __builtin_amdgcn_mfma_f32_16x16x32_bf16(
        __builtin_bit_cast(bf16x8, a), __builtin_bit_cast(bf16x8, b), c, 0, 0, 0);
}

// pack 4 f32 -> 4 bf16 (RNE) via v_cvt_pk
static __device__ __forceinline__ void cvtpk4(float a0, float a1, float a2, float a3,
                                              unsigned& d0, unsigned& d1) {
    asm("v_cvt_pk_bf16_f32 %0, %1, %2" : "=v"(d0) : "v"(a0), "v"(a1));
    asm("v_cvt_pk_bf16_f32 %0, %1, %2" : "=v"(d1) : "v"(a2), "v"(a3));
}

// ---------------------------------------------------------------------------
// Kernel 1: W [1024][64] f32 (x3) -> Wt [192][1024] bf16 (unchanged, verified)
// ---------------------------------------------------------------------------
__global__ __launch_bounds__(256) void wprep(const float* __restrict__ Wk,
                                             const float* __restrict__ Wq,
                                             const float* __restrict__ Wv,
                                             unsigned short* __restrict__ wt) {
    __shared__ float tile[64][65];
    const int arr = blockIdx.x >> 4, ct = blockIdx.x & 15;
    const float* W = (arr == 0) ? Wk : ((arr == 1) ? Wq : Wv);
    const int tid = threadIdx.x;
    {
        int c = tid >> 2, seg = (tid & 3) << 4;
        const float* src = W + (size_t)(ct * 64 + c) * 64 + seg;
#pragma unroll
        for (int j = 0; j < 16; j += 4) {
            f32x4 v4 = *(const f32x4*)(src + j);
            tile[c][seg + j + 0] = v4[0];
            tile[c][seg + j + 1] = v4[1];
            tile[c][seg + j + 2] = v4[2];
            tile[c][seg + j + 3] = v4[3];
        }
    }
    __syncthreads();
    {
        int h = tid >> 2, cs = (tid & 3) << 4;
        unsigned short* dst = wt + (size_t)(arr * 64 + h) * 1024 + ct * 64 + cs;
#pragma unroll
        for (int j = 0; j < 16; ++j) dst[j] = f2bf(tile[cs + j][h]);
    }
}

// ---------------------------------------------------------------------------
// Kernel 2 (v2): LDS-FREE direct-fragment projection GEMM.
// C[16384][192] = idx[16384][1024] x Wt^T. BM=32, grid=512 (2 blocks/CU,
// 8 waves/CU). Each lane loads its A-fragment directly from idx (f32 ->
// cvt_pk bf16 in-register; 4 waves share rows via L1) and B-fragment
// directly from L2-resident Wt. No LDS, no barriers -> compiler pipelines
// the fully unrolled 16 K-steps freely. Wave w owns n-cols 48w..48w+47.
// ---------------------------------------------------------------------------
__global__ __launch_bounds__(256) void proj_gemm(const float* __restrict__ idx,
                                                 const unsigned short* __restrict__ wt,
                                                 unsigned short* __restrict__ kw,
                                                 unsigned short* __restrict__ qw,
                                                 unsigned short* __restrict__ vtw) {
    const int tid = threadIdx.x;
    const int lane = tid & 63, w = tid >> 6;
    const int g = lane >> 4, l15 = lane & 15;
    const int m0 = blockIdx.x * 32;

    const float* arow0 = idx + (size_t)(m0 + l15) * 1024;
    const float* arow1 = idx + (size_t)(m0 + 16 + l15) * 1024;
    const unsigned short* brow0 = wt + (size_t)((3 * w + 0) * 16 + l15) * 1024;
    const unsigned short* brow1 = wt + (size_t)((3 * w + 1) * 16 + l15) * 1024;
    const unsigned short* brow2 = wt + (size_t)((3 * w + 2) * 16 + l15) * 1024;

    f32x4 acc[2][3] = {};

#pragma unroll
    for (int kt = 0; kt < 16; ++kt) {
        const int k0 = kt * 64;
        u16x8 a[2][2];   // [ks][mf]
#pragma unroll
        for (int mf = 0; mf < 2; ++mf) {
            const float* ar = mf ? arow1 : arow0;
#pragma unroll
            for (int ks = 0; ks < 2; ++ks) {
                f32x4 f0 = *(const f32x4*)(ar + k0 + ks * 32 + g * 8);
                f32x4 f1 = *(const f32x4*)(ar + k0 + ks * 32 + g * 8 + 4);
                unsigned d0, d1, d2, d3;
                cvtpk4(f0[0], f0[1], f0[2], f0[3], d0, d1);
                cvtpk4(f1[0], f1[1], f1[2], f1[3], d2, d3);
                uint4 u; u.x = d0; u.y = d1; u.z = d2; u.w = d3;
                a[ks][mf] = __builtin_bit_cast(u16x8, u);
            }
        }
#pragma unroll
        for (int ks = 0; ks < 2; ++ks) {
            u16x8 b0 = *(const u16x8*)(brow0 + k0 + ks * 32 + g * 8);
            u16x8 b1 = *(const u16x8*)(brow1 + k0 + ks * 32 + g * 8);
            u16x8 b2 = *(const u16x8*)(brow2 + k0 + ks * 32 + g * 8);
#pragma unroll
            for (int mf = 0; mf < 2; ++mf) {
                acc[mf][0] = mfma16(a[ks][mf], b0, acc[mf][0]);
                acc[mf][1] = mfma16(a[ks][mf], b1, acc[mf][1]);
                acc[mf][2] = mfma16(a[ks][mf], b2, acc[mf][2]);
            }
        }
    }

    // epilogue: D layout col=lane&15, row=g*4+reg
#pragma unroll
    for (int nf = 0; nf < 3; ++nf) {
        int nb = 3 * w + nf;             // 16-col block 0..11
        int arr = nb >> 2;               // 0=k 1=q 2=v
        int nloc = ((nb & 3) << 4) + l15;
#pragma unroll
        for (int mf = 0; mf < 2; ++mf) {
            f32x4 ac = acc[mf][nf];
            int row = m0 + mf * 16 + g * 4;
            if (arr == 2) {
                u16x4 pk = {f2bf(ac[0]), f2bf(ac[1]), f2bf(ac[2]), f2bf(ac[3])};
                *(u16x4*)&vtw[(size_t)nloc * BT_ + row] = pk;   // vT[h][row]
            } else {
                unsigned short* dst = arr ? qw : kw;
                dst[(size_t)(row + 0) * 64 + nloc] = f2bf(ac[0]);
                dst[(size_t)(row + 1) * 64 + nloc] = f2bf(ac[1]);
                dst[(size_t)(row + 2) * 64 + nloc] = f2bf(ac[2]);
                dst[(size_t)(row + 3) * 64 + nloc] = f2bf(ac[3]);
            }
        }
    }
}

// ---------------------------------------------------------------------------
// Kernel 3: causal attention, v6 — static-max softmax + 2-ITEM PIPELINE.
// Same decomposition as v5 (block = (b, pair(j,127-j)), wave strides s-tiles
// by 8, XCD-local b=bid&7, combine via LDS). New: each wave interleaves two
// independent items (st, st+8) so ~32 loads + 2 full chains are in flight
// per wave -> latency-stall coverage doubles at unchanged occupancy.
// grid: 512 blocks x 512 threads
// ---------------------------------------------------------------------------
__global__ __launch_bounds__(512, 2) void attn(const unsigned short* __restrict__ kw,
                                               const unsigned short* __restrict__ qw,
                                               const unsigned short* __restrict__ vtw,
                                               float* __restrict__ out) {
    // [loop] per-wave p double-buffer: 8 waves x 2 x 4KB = 64KB
    // [combine] O[8][32][64] f32 (aliases p) + l 1KB
    __shared__ __align__(16) char smem[8 * 32 * 64 * 4 + 8 * 32 * 4];  // 66560 B
    const int tid = threadIdx.x;
    const int w = tid >> 6, lane = tid & 63;
    const int g = lane >> 4, l15 = lane & 15;
    const int bid = blockIdx.x;
    const int b = bid & 7;                 // XCD-local batch
    const int j = bid >> 3;                // pair index 0..63
    const int t0A = j * 16;
    const int t0B = (127 - j) * 16;
    const size_t base = (size_t)b * T_;
    const int nSA = (t0A >> 6) + 1;        // s-tiles needed by tile A
    const int nSB = (t0B >> 6) + 1;        // s-tiles needed by tile B (>= 17)
    unsigned short* pb0 = (unsigned short*)smem + w * 4096;
    unsigned short* pb1 = pb0 + 2048;
    const float SCL = 0.125f * 1.44269504f;   // exp2-domain scale
    const float MOFF = 16.0f;                 // static max (exp2 domain)

    // k fragments for both tiles (tf=0 -> tile A, tf=1 -> tile B)
    u16x8 kf[2][2];
#pragma unroll
    for (int tf = 0; tf < 2; ++tf) {
        const unsigned short* kr = kw + (size_t)(base + (tf ? t0B : t0A) + l15) * 64;
        kf[tf][0] = *(const u16x8*)(kr + g * 8);
        kf[tf][1] = *(const u16x8*)(kr + 32 + g * 8);
    }

    f32x4 o[4][2] = {};
    float l_lane[2] = {0.f, 0.f};

    auto load_q = [&](int s0, u16x8 (&a)[2][4]) {
#pragma unroll
        for (int ks = 0; ks < 2; ++ks)
#pragma unroll
            for (int sf = 0; sf < 4; ++sf)
                a[ks][sf] = *(const u16x8*)(qw + (size_t)(base + s0 + sf * 16 + l15) * 64 +
                                            ks * 32 + g * 8);
    };
    auto load_v = [&](int s0, u16x8 (&vf)[2][4]) {
#pragma unroll
        for (int ks = 0; ks < 2; ++ks)
#pragma unroll
            for (int mf = 0; mf < 4; ++mf)
                vf[ks][mf] = *(const u16x8*)(vtw + (size_t)(mf * 16 + l15) * BT_ +
                                             base + s0 + ks * 32 + g * 8);
    };
    auto do_qk = [&](u16x8 (&a)[2][4], f32x4 (&s_)[4][2], bool doA) {
#pragma unroll
        for (int sf = 0; sf < 4; ++sf) { s_[sf][0] = f32x4{}; s_[sf][1] = f32x4{}; }
        __builtin_amdgcn_s_setprio(1);
#pragma unroll
        for (int ks = 0; ks < 2; ++ks)
#pragma unroll
            for (int sf = 0; sf < 4; ++sf)
                s_[sf][1] = mfma16(a[ks][sf], kf[1][ks], s_[sf][1]);
        if (doA) {
#pragma unroll
            for (int ks = 0; ks < 2; ++ks)
#pragma unroll
                for (int sf = 0; sf < 4; ++sf)
                    s_[sf][0] = mfma16(a[ks][sf], kf[0][ks], s_[sf][0]);
        }
        __builtin_amdgcn_s_setprio(0);
    };
    auto do_sm = [&](f32x4 (&s_)[4][2], int s0, unsigned short* p_cur, bool doA) {
#pragma unroll
        for (int tf_ = 1; tf_ >= 0; --tf_) {
            if (tf_ == 0 && !doA) continue;
            const int tbase_ = tf_ ? t0B : t0A;
            float pv[4][4];
#pragma unroll
            for (int sf = 0; sf < 4; ++sf)
#pragma unroll
                for (int r = 0; r < 4; ++r)
                    pv[sf][r] = exp2f(fmaf(s_[sf][tf_][r], SCL, -MOFF));
            if (s0 + 63 > tbase_) {            // diagonal tile: zero masked
                const int t_ = tbase_ + l15;
#pragma unroll
                for (int sf = 0; sf < 4; ++sf)
#pragma unroll
                    for (int r = 0; r < 4; ++r) {
                        int sg = s0 + sf * 16 + g * 4 + r;
                        if (sg > t_) pv[sf][r] = 0.f;
                    }
            }
            float lacc = 0.f;
#pragma unroll
            for (int sf = 0; sf < 4; ++sf)
                lacc += (pv[sf][0] + pv[sf][1]) + (pv[sf][2] + pv[sf][3]);
            l_lane[tf_] += lacc;
            const int trow = tf_ * 16 + l15;
#pragma unroll
            for (int sf = 0; sf < 4; ++sf) {
                unsigned r0, r1;
                cvtpk4(pv[sf][0], pv[sf][1], pv[sf][2], pv[sf][3], r0, r1);
                int u16i = (sf * 2 + (g >> 1)) ^ (l15 & 7);
                uint2 pk; pk.x = r0; pk.y = r1;
                *(uint2*)&p_cur[trow * 64 + u16i * 8 + (g & 1) * 4] = pk;
            }
        }
    };
    auto do_pv = [&](u16x8 (&vf)[2][4], unsigned short* p_cur, bool doA) {
        __builtin_amdgcn_s_setprio(1);
#pragma unroll
        for (int ks = 0; ks < 2; ++ks) {
            u16x8 bp1 = *(const u16x8*)&p_cur[(16 + l15) * 64 +
                                              (((ks * 4 + g) ^ (l15 & 7)) * 8)];
#pragma unroll
            for (int mf = 0; mf < 4; ++mf)
                o[mf][1] = mfma16(vf[ks][mf], bp1, o[mf][1]);
            if (doA) {
                u16x8 bp0 = *(const u16x8*)&p_cur[l15 * 64 +
                                                  (((ks * 4 + g) ^ (l15 & 7)) * 8)];
#pragma unroll
                for (int mf = 0; mf < 4; ++mf)
                    o[mf][0] = mfma16(vf[ks][mf], bp0, o[mf][0]);
            }
        }
        __builtin_amdgcn_s_setprio(0);
    };

    // ---- 2-item pipelined main loop ----
    u16x8 aA[2][4], aB[2][4];
    int st = w;
    load_q(st << 6, aA);
    for (; st + 8 < nSB; st += 16) {
        const int s0a = st << 6, s0b = (st + 8) << 6;
        const bool dA0 = (st < nSA), dA1 = (st + 8 < nSA);
        load_q(s0b, aB);                       // item-B q in flight during item-A work
        f32x4 sA[4][2];
        do_qk(aA, sA, dA0);
        u16x8 vfA[2][4];
        load_v(s0a, vfA);                      // covered by sm_a + qk_b + sm_b
        do_sm(sA, s0a, pb0, dA0);
        f32x4 sB[4][2];
        do_qk(aB, sB, dA1);
        u16x8 vfB[2][4];
        load_v(s0b, vfB);
        if (st + 16 < nSB) load_q((st + 16) << 6, aA);   // next pair's first q
        do_sm(sB, s0b, pb1, dA1);
        do_pv(vfA, pb0, dA0);
        do_pv(vfB, pb1, dA1);
    }
    if (st < nSB) {                            // tail single item
        const int s0a = st << 6;
        const bool dA0 = (st < nSA);
        f32x4 sA[4][2];
        do_qk(aA, sA, dA0);
        u16x8 vfA[2][4];
        load_v(s0a, vfA);
        do_sm(sA, s0a, pb0, dA0);
        do_pv(vfA, pb0, dA0);
    }

    // ---- combine: plain sums (static max -> no weights) ----
    float* O_lds = (float*)smem;                       // [w][t][64]; w's slice
    float* l_lds = (float*)(smem + 8 * 32 * 64 * 4);   //   aliases its own p-dbuf
#pragma unroll
    for (int tf = 0; tf < 2; ++tf) {
        float ls = l_lane[tf];
        ls += __shfl_xor(ls, 16);
        ls += __shfl_xor(ls, 32);
        int t = tf * 16 + l15;
        if (g == 0) l_lds[w * 32 + t] = ls;
#pragma unroll
        for (int mf = 0; mf < 4; ++mf) {
            int su = (mf * 4 + g) ^ l15;
            *(f32x4*)&O_lds[(size_t)(w * 32 + t) * 64 + su * 4] = o[mf][tf];
        }
    }
    __syncthreads();
    {
        int t = tid >> 4, u = tid & 15;
        float L = 0.f;
        f32x4 acc = {};
#pragma unroll
        for (int ww = 0; ww < 8; ++ww) {
            L += l_lds[ww * 32 + t];
            acc += *(const f32x4*)&O_lds[(size_t)(ww * 32 + t) * 64 +
                                         ((u ^ (t & 15)) * 4)];
        }
        float inv = 1.f / L;
        int trow = (t < 16) ? (t0A + t) : (t0B + (t - 16));
        *(f32x4*)(out + (size_t)(base + trow) * 64 + u * 4) = acc * inv;
    }
}

// ---------------------------------------------------------------------------
extern "C" void kernel_launch(void* const* d_in, const int* in_sizes, int n_in,
                              void* d_out, int out_size, void* d_ws, size_t ws_size,
                              hipStream_t stream) {
    const float* idx = (const float*)d_in[0];
    const float* Wk = (const float*)d_in[1];
    const float* Wq = (const float*)d_in[2];
    const float* Wv = (const float*)d_in[3];
    float* out = (float*)d_out;

    unsigned short* wt = (unsigned short*)d_ws;
    unsigned short* kw = wt + 192 * 1024;
    unsigned short* qw = kw + (size_t)BT_ * 64;
    unsigned short* vtw = qw + (size_t)BT_ * 64;

    wprep<<<48, 256, 0, stream>>>(Wk, Wq, Wv, wt);
    proj_gemm<<<512, 256, 0, stream>>>(idx, wt, kw, qw, vtw);
    attn<<<512, 512, 0, stream>>>(kw, qw, vtw, out);
}

// Round 7
// 57.321 us; speedup vs baseline: 1.5624x; 1.5624x over previous
//
#include <hip/hip_runtime.h>

#define B_ 8
#define T_ 2048
#define C_ 1024
#define H_ 64
#define BT_ (B_ * T_)

typedef float f32x4 __attribute__((ext_vector_type(4)));
typedef unsigned short u16x4 __attribute__((ext_vector_type(4)));
typedef unsigned short u16x8 __attribute__((ext_vector_type(8)));
typedef __bf16 bf16x8 __attribute__((ext_vector_type(8)));

// f32 -> bf16 round-to-nearest-even
static __device__ __forceinline__ unsigned short f2bf(float f) {
    unsigned int u = __builtin_bit_cast(unsigned int, f);
    u = (u + 0x7FFFu + ((u >> 16) & 1u)) >> 16;
    return (unsigned short)u;
}

static __device__ __forceinline__ f32x4 mfma16(u16x8 a, u16x8 b, f32x4 c) {
    return __builtin_amdgcn_mfma_f32_16x16x32_bf16(
        __builtin_bit_cast(bf16x8, a), __builtin_bit_cast(bf16x8, b), c, 0, 0, 0);
}

// pack 4 f32 -> 4 bf16 (RNE) via v_cvt_pk
static __device__ __forceinline__ void cvtpk4(float a0, float a1, float a2, float a3,
                                              unsigned& d0, unsigned& d1) {
    asm("v_cvt_pk_bf16_f32 %0, %1, %2" : "=v"(d0) : "v"(a0), "v"(a1));
    asm("v_cvt_pk_bf16_f32 %0, %1, %2" : "=v"(d1) : "v"(a2), "v"(a3));
}

// ---------------------------------------------------------------------------
// Kernel 1: W [1024][64] f32 (x3) -> Wt [192][1024] bf16 (unchanged, verified)
// ---------------------------------------------------------------------------
__global__ __launch_bounds__(256) void wprep(const float* __restrict__ Wk,
                                             const float* __restrict__ Wq,
                                             const float* __restrict__ Wv,
                                             unsigned short* __restrict__ wt) {
    __shared__ float tile[64][65];
    const int arr = blockIdx.x >> 4, ct = blockIdx.x & 15;
    const float* W = (arr == 0) ? Wk : ((arr == 1) ? Wq : Wv);
    const int tid = threadIdx.x;
    {
        int c = tid >> 2, seg = (tid & 3) << 4;
        const float* src = W + (size_t)(ct * 64 + c) * 64 + seg;
#pragma unroll
        for (int j = 0; j < 16; j += 4) {
            f32x4 v4 = *(const f32x4*)(src + j);
            tile[c][seg + j + 0] = v4[0];
            tile[c][seg + j + 1] = v4[1];
            tile[c][seg + j + 2] = v4[2];
            tile[c][seg + j + 3] = v4[3];
        }
    }
    __syncthreads();
    {
        int h = tid >> 2, cs = (tid & 3) << 4;
        unsigned short* dst = wt + (size_t)(arr * 64 + h) * 1024 + ct * 64 + cs;
#pragma unroll
        for (int j = 0; j < 16; ++j) dst[j] = f2bf(tile[cs + j][h]);
    }
}

// ---------------------------------------------------------------------------
// Kernel 2: kqv projection GEMM — REVERTED to the round-5 LDS-staged version
// (verified ~14 us). Round-6 "direct-fragment" variant was a 16-row gather
// (4x VMEM issue, 68 VGPR, no load pipelining) -> 62 us. Lesson recorded.
// BM=64, BK=64, 4 waves; coalesced f32x4 idx loads; double-buffered LDS.
// grid: 256 blocks, 256 threads
// ---------------------------------------------------------------------------
__global__ __launch_bounds__(256) void proj_gemm(const float* __restrict__ idx,
                                                 const unsigned short* __restrict__ wt,
                                                 unsigned short* __restrict__ kw,
                                                 unsigned short* __restrict__ qw,
                                                 unsigned short* __restrict__ vtw) {
    __shared__ unsigned short As[2][64 * 64];    // 16 KB
    __shared__ unsigned short Bs[2][192 * 64];   // 48 KB
    const int tid = threadIdx.x;
    const int lane = tid & 63, w = tid >> 6;
    const int g = lane >> 4, l15 = lane & 15;
    const int m0 = blockIdx.x * 64;
    const int arow = tid >> 2, aseg = tid & 3;

    f32x4 acc[4][3] = {};
    f32x4 areg[4];
    u16x8 breg[6];

    {
        const float* src = idx + (size_t)(m0 + arow) * 1024 + aseg * 16;
        areg[0] = ((const f32x4*)src)[0];
        areg[1] = ((const f32x4*)src)[1];
        areg[2] = ((const f32x4*)src)[2];
        areg[3] = ((const f32x4*)src)[3];
#pragma unroll
        for (int i = 0; i < 6; ++i) {
            int slot = i * 256 + tid, n = slot >> 3, u = slot & 7;
            breg[i] = *(const u16x8*)(wt + (size_t)n * 1024 + u * 8);
        }
        u16x8 c0, c1;
#pragma unroll
        for (int e = 0; e < 4; ++e) {
            c0[e] = f2bf(areg[0][e]); c0[e + 4] = f2bf(areg[1][e]);
            c1[e] = f2bf(areg[2][e]); c1[e + 4] = f2bf(areg[3][e]);
        }
        *(u16x8*)&As[0][arow * 64 + (((aseg * 2) ^ (arow & 7)) * 8)] = c0;
        *(u16x8*)&As[0][arow * 64 + (((aseg * 2 + 1) ^ (arow & 7)) * 8)] = c1;
#pragma unroll
        for (int i = 0; i < 6; ++i) {
            int slot = i * 256 + tid, n = slot >> 3, u = slot & 7;
            *(u16x8*)&Bs[0][n * 64 + ((u ^ (n & 7)) * 8)] = breg[i];
        }
    }
    __syncthreads();

    int cur = 0;
    for (int kt = 0; kt < 16; ++kt) {
        if (kt < 15) {
            int k0n = (kt + 1) * 64;
            const float* src = idx + (size_t)(m0 + arow) * 1024 + k0n + aseg * 16;
            areg[0] = ((const f32x4*)src)[0];
            areg[1] = ((const f32x4*)src)[1];
            areg[2] = ((const f32x4*)src)[2];
            areg[3] = ((const f32x4*)src)[3];
#pragma unroll
            for (int i = 0; i < 6; ++i) {
                int slot = i * 256 + tid, n = slot >> 3, u = slot & 7;
                breg[i] = *(const u16x8*)(wt + (size_t)n * 1024 + k0n + u * 8);
            }
        }
#pragma unroll
        for (int ks = 0; ks < 2; ++ks) {
            u16x8 a[4], b[3];
#pragma unroll
            for (int mf = 0; mf < 4; ++mf)
                a[mf] = *(const u16x8*)&As[cur][(mf * 16 + l15) * 64 +
                                                (((ks * 4 + g) ^ (l15 & 7)) * 8)];
#pragma unroll
            for (int nf = 0; nf < 3; ++nf) {
                int n = w * 48 + nf * 16 + l15;
                b[nf] = *(const u16x8*)&Bs[cur][n * 64 + (((ks * 4 + g) ^ (n & 7)) * 8)];
            }
#pragma unroll
            for (int mf = 0; mf < 4; ++mf)
#pragma unroll
                for (int nf = 0; nf < 3; ++nf)
                    acc[mf][nf] = mfma16(a[mf], b[nf], acc[mf][nf]);
        }
        if (kt < 15) {
            u16x8 c0, c1;
#pragma unroll
            for (int e = 0; e < 4; ++e) {
                c0[e] = f2bf(areg[0][e]); c0[e + 4] = f2bf(areg[1][e]);
                c1[e] = f2bf(areg[2][e]); c1[e + 4] = f2bf(areg[3][e]);
            }
            *(u16x8*)&As[cur ^ 1][arow * 64 + (((aseg * 2) ^ (arow & 7)) * 8)] = c0;
            *(u16x8*)&As[cur ^ 1][arow * 64 + (((aseg * 2 + 1) ^ (arow & 7)) * 8)] = c1;
#pragma unroll
            for (int i = 0; i < 6; ++i) {
                int slot = i * 256 + tid, n = slot >> 3, u = slot & 7;
                *(u16x8*)&Bs[cur ^ 1][n * 64 + ((u ^ (n & 7)) * 8)] = breg[i];
            }
        }
        __syncthreads();
        cur ^= 1;
    }

#pragma unroll
    for (int nf = 0; nf < 3; ++nf) {
        int nb = 3 * w + nf;
        int arr = nb >> 2;
        int nloc = ((nb & 3) << 4) + l15;
#pragma unroll
        for (int mf = 0; mf < 4; ++mf) {
            f32x4 ac = acc[mf][nf];
            int row = m0 + mf * 16 + g * 4;
            if (arr == 2) {
                u16x4 pk = {f2bf(ac[0]), f2bf(ac[1]), f2bf(ac[2]), f2bf(ac[3])};
                *(u16x4*)&vtw[(size_t)nloc * BT_ + row] = pk;
            } else {
                unsigned short* dst = arr ? qw : kw;
                dst[(size_t)(row + 0) * 64 + nloc] = f2bf(ac[0]);
                dst[(size_t)(row + 1) * 64 + nloc] = f2bf(ac[1]);
                dst[(size_t)(row + 2) * 64 + nloc] = f2bf(ac[2]);
                dst[(size_t)(row + 3) * 64 + nloc] = f2bf(ac[3]);
            }
        }
    }
}

// ---------------------------------------------------------------------------
// Kernel 3: causal attention, v6 (unchanged) — static-max softmax + 2-item
// pipeline. Inferred ~23 us in round 6 (was ~37 before the pipeline).
// grid: 512 blocks x 512 threads
// ---------------------------------------------------------------------------
__global__ __launch_bounds__(512, 2) void attn(const unsigned short* __restrict__ kw,
                                               const unsigned short* __restrict__ qw,
                                               const unsigned short* __restrict__ vtw,
                                               float* __restrict__ out) {
    // [loop] per-wave p double-buffer: 8 waves x 2 x 4KB = 64KB
    // [combine] O[8][32][64] f32 (aliases p) + l 1KB
    __shared__ __align__(16) char smem[8 * 32 * 64 * 4 + 8 * 32 * 4];  // 66560 B
    const int tid = threadIdx.x;
    const int w = tid >> 6, lane = tid & 63;
    const int g = lane >> 4, l15 = lane & 15;
    const int bid = blockIdx.x;
    const int b = bid & 7;                 // XCD-local batch
    const int j = bid >> 3;                // pair index 0..63
    const int t0A = j * 16;
    const int t0B = (127 - j) * 16;
    const size_t base = (size_t)b * T_;
    const int nSA = (t0A >> 6) + 1;        // s-tiles needed by tile A
    const int nSB = (t0B >> 6) + 1;        // s-tiles needed by tile B (>= 17)
    unsigned short* pb0 = (unsigned short*)smem + w * 4096;
    unsigned short* pb1 = pb0 + 2048;
    const float SCL = 0.125f * 1.44269504f;   // exp2-domain scale
    const float MOFF = 16.0f;                 // static max (exp2 domain)

    // k fragments for both tiles (tf=0 -> tile A, tf=1 -> tile B)
    u16x8 kf[2][2];
#pragma unroll
    for (int tf = 0; tf < 2; ++tf) {
        const unsigned short* kr = kw + (size_t)(base + (tf ? t0B : t0A) + l15) * 64;
        kf[tf][0] = *(const u16x8*)(kr + g * 8);
        kf[tf][1] = *(const u16x8*)(kr + 32 + g * 8);
    }

    f32x4 o[4][2] = {};
    float l_lane[2] = {0.f, 0.f};

    auto load_q = [&](int s0, u16x8 (&a)[2][4]) {
#pragma unroll
        for (int ks = 0; ks < 2; ++ks)
#pragma unroll
            for (int sf = 0; sf < 4; ++sf)
                a[ks][sf] = *(const u16x8*)(qw + (size_t)(base + s0 + sf * 16 + l15) * 64 +
                                            ks * 32 + g * 8);
    };
    auto load_v = [&](int s0, u16x8 (&vf)[2][4]) {
#pragma unroll
        for (int ks = 0; ks < 2; ++ks)
#pragma unroll
            for (int mf = 0; mf < 4; ++mf)
                vf[ks][mf] = *(const u16x8*)(vtw + (size_t)(mf * 16 + l15) * BT_ +
                                             base + s0 + ks * 32 + g * 8);
    };
    auto do_qk = [&](u16x8 (&a)[2][4], f32x4 (&s_)[4][2], bool doA) {
#pragma unroll
        for (int sf = 0; sf < 4; ++sf) { s_[sf][0] = f32x4{}; s_[sf][1] = f32x4{}; }
        __builtin_amdgcn_s_setprio(1);
#pragma unroll
        for (int ks = 0; ks < 2; ++ks)
#pragma unroll
            for (int sf = 0; sf < 4; ++sf)
                s_[sf][1] = mfma16(a[ks][sf], kf[1][ks], s_[sf][1]);
        if (doA) {
#pragma unroll
            for (int ks = 0; ks < 2; ++ks)
#pragma unroll
                for (int sf = 0; sf < 4; ++sf)
                    s_[sf][0] = mfma16(a[ks][sf], kf[0][ks], s_[sf][0]);
        }
        __builtin_amdgcn_s_setprio(0);
    };
    auto do_sm = [&](f32x4 (&s_)[4][2], int s0, unsigned short* p_cur, bool doA) {
#pragma unroll
        for (int tf_ = 1; tf_ >= 0; --tf_) {
            if (tf_ == 0 && !doA) continue;
            const int tbase_ = tf_ ? t0B : t0A;
            float pv[4][4];
#pragma unroll
            for (int sf = 0; sf < 4; ++sf)
#pragma unroll
                for (int r = 0; r < 4; ++r)
                    pv[sf][r] = exp2f(fmaf(s_[sf][tf_][r], SCL, -MOFF));
            if (s0 + 63 > tbase_) {            // diagonal tile: zero masked
                const int t_ = tbase_ + l15;
#pragma unroll
                for (int sf = 0; sf < 4; ++sf)
#pragma unroll
                    for (int r = 0; r < 4; ++r) {
                        int sg = s0 + sf * 16 + g * 4 + r;
                        if (sg > t_) pv[sf][r] = 0.f;
                    }
            }
            float lacc = 0.f;
#pragma unroll
            for (int sf = 0; sf < 4; ++sf)
                lacc += (pv[sf][0] + pv[sf][1]) + (pv[sf][2] + pv[sf][3]);
            l_lane[tf_] += lacc;
            const int trow = tf_ * 16 + l15;
#pragma unroll
            for (int sf = 0; sf < 4; ++sf) {
                unsigned r0, r1;
                cvtpk4(pv[sf][0], pv[sf][1], pv[sf][2], pv[sf][3], r0, r1);
                int u16i = (sf * 2 + (g >> 1)) ^ (l15 & 7);
                uint2 pk; pk.x = r0; pk.y = r1;
                *(uint2*)&p_cur[trow * 64 + u16i * 8 + (g & 1) * 4] = pk;
            }
        }
    };
    auto do_pv = [&](u16x8 (&vf)[2][4], unsigned short* p_cur, bool doA) {
        __builtin_amdgcn_s_setprio(1);
#pragma unroll
        for (int ks = 0; ks < 2; ++ks) {
            u16x8 bp1 = *(const u16x8*)&p_cur[(16 + l15) * 64 +
                                              (((ks * 4 + g) ^ (l15 & 7)) * 8)];
#pragma unroll
            for (int mf = 0; mf < 4; ++mf)
                o[mf][1] = mfma16(vf[ks][mf], bp1, o[mf][1]);
            if (doA) {
                u16x8 bp0 = *(const u16x8*)&p_cur[l15 * 64 +
                                                  (((ks * 4 + g) ^ (l15 & 7)) * 8)];
#pragma unroll
                for (int mf = 0; mf < 4; ++mf)
                    o[mf][0] = mfma16(vf[ks][mf], bp0, o[mf][0]);
            }
        }
        __builtin_amdgcn_s_setprio(0);
    };

    // ---- 2-item pipelined main loop ----
    u16x8 aA[2][4], aB[2][4];
    int st = w;
    load_q(st << 6, aA);
    for (; st + 8 < nSB; st += 16) {
        const int s0a = st << 6, s0b = (st + 8) << 6;
        const bool dA0 = (st < nSA), dA1 = (st + 8 < nSA);
        load_q(s0b, aB);                       // item-B q in flight during item-A work
        f32x4 sA[4][2];
        do_qk(aA, sA, dA0);
        u16x8 vfA[2][4];
        load_v(s0a, vfA);                      // covered by sm_a + qk_b + sm_b
        do_sm(sA, s0a, pb0, dA0);
        f32x4 sB[4][2];
        do_qk(aB, sB, dA1);
        u16x8 vfB[2][4];
        load_v(s0b, vfB);
        if (st + 16 < nSB) load_q((st + 16) << 6, aA);   // next pair's first q
        do_sm(sB, s0b, pb1, dA1);
        do_pv(vfA, pb0, dA0);
        do_pv(vfB, pb1, dA1);
    }
    if (st < nSB) {                            // tail single item
        const int s0a = st << 6;
        const bool dA0 = (st < nSA);
        f32x4 sA[4][2];
        do_qk(aA, sA, dA0);
        u16x8 vfA[2][4];
        load_v(s0a, vfA);
        do_sm(sA, s0a, pb0, dA0);
        do_pv(vfA, pb0, dA0);
    }

    // ---- combine: plain sums (static max -> no weights) ----
    float* O_lds = (float*)smem;                       // [w][t][64]; w's slice
    float* l_lds = (float*)(smem + 8 * 32 * 64 * 4);   //   aliases its own p-dbuf
#pragma unroll
    for (int tf = 0; tf < 2; ++tf) {
        float ls = l_lane[tf];
        ls += __shfl_xor(ls, 16);
        ls += __shfl_xor(ls, 32);
        int t = tf * 16 + l15;
        if (g == 0) l_lds[w * 32 + t] = ls;
#pragma unroll
        for (int mf = 0; mf < 4; ++mf) {
            int su = (mf * 4 + g) ^ l15;
            *(f32x4*)&O_lds[(size_t)(w * 32 + t) * 64 + su * 4] = o[mf][tf];
        }
    }
    __syncthreads();
    {
        int t = tid >> 4, u = tid & 15;
        float L = 0.f;
        f32x4 acc = {};
#pragma unroll
        for (int ww = 0; ww < 8; ++ww) {
            L += l_lds[ww * 32 + t];
            acc += *(const f32x4*)&O_lds[(size_t)(ww * 32 + t) * 64 +
                                         ((u ^ (t & 15)) * 4)];
        }
        float inv = 1.f / L;
        int trow = (t < 16) ? (t0A + t) : (t0B + (t - 16));
        *(f32x4*)(out + (size_t)(base + trow) * 64 + u * 4) = acc * inv;
    }
}

// ---------------------------------------------------------------------------
extern "C" void kernel_launch(void* const* d_in, const int* in_sizes, int n_in,
                              void* d_out, int out_size, void* d_ws, size_t ws_size,
                              hipStream_t stream) {
    const float* idx = (const float*)d_in[0];
    const float* Wk = (const float*)d_in[1];
    const float* Wq = (const float*)d_in[2];
    const float* Wv = (const float*)d_in[3];
    float* out = (float*)d_out;

    unsigned short* wt = (unsigned short*)d_ws;
    unsigned short* kw = wt + 192 * 1024;
    unsigned short* qw = kw + (size_t)BT_ * 64;
    unsigned short* vtw = qw + (size_t)BT_ * 64;

    wprep<<<48, 256, 0, stream>>>(Wk, Wq, Wv, wt);
    proj_gemm<<<256, 256, 0, stream>>>(idx, wt, kw, qw, vtw);
    attn<<<512, 512, 0, stream>>>(kw, qw, vtw, out);
}

// Round 8
// 49.660 us; speedup vs baseline: 1.8035x; 1.1543x over previous
//
#include <hip/hip_runtime.h>

#define B_ 8
#define T_ 2048
#define C_ 1024
#define H_ 64
#define BT_ (B_ * T_)

typedef float f32x4 __attribute__((ext_vector_type(4)));
typedef unsigned short u16x4 __attribute__((ext_vector_type(4)));
typedef unsigned short u16x8 __attribute__((ext_vector_type(8)));
typedef __bf16 bf16x8 __attribute__((ext_vector_type(8)));

// f32 -> bf16 round-to-nearest-even
static __device__ __forceinline__ unsigned short f2bf(float f) {
    unsigned int u = __builtin_bit_cast(unsigned int, f);
    u = (u + 0x7FFFu + ((u >> 16) & 1u)) >> 16;
    return (unsigned short)u;
}

static __device__ __forceinline__ f32x4 mfma16(u16x8 a, u16x8 b, f32x4 c) {
    return __builtin_amdgcn_mfma_f32_16x16x32_bf16(
        __builtin_bit_cast(bf16x8, a), __builtin_bit_cast(bf16x8, b), c, 0, 0, 0);
}

// pack 4 f32 -> 4 bf16 (RNE) via v_cvt_pk
static __device__ __forceinline__ void cvtpk4(float a0, float a1, float a2, float a3,
                                              unsigned& d0, unsigned& d1) {
    asm("v_cvt_pk_bf16_f32 %0, %1, %2" : "=v"(d0) : "v"(a0), "v"(a1));
    asm("v_cvt_pk_bf16_f32 %0, %1, %2" : "=v"(d1) : "v"(a2), "v"(a3));
}

// ---------------------------------------------------------------------------
// Kernel 1: W [1024][64] f32 (x3) -> Wt [192][1024] bf16 (unchanged, verified)
// ---------------------------------------------------------------------------
__global__ __launch_bounds__(256) void wprep(const float* __restrict__ Wk,
                                             const float* __restrict__ Wq,
                                             const float* __restrict__ Wv,
                                             unsigned short* __restrict__ wt) {
    __shared__ float tile[64][65];
    const int arr = blockIdx.x >> 4, ct = blockIdx.x & 15;
    const float* W = (arr == 0) ? Wk : ((arr == 1) ? Wq : Wv);
    const int tid = threadIdx.x;
    {
        int c = tid >> 2, seg = (tid & 3) << 4;
        const float* src = W + (size_t)(ct * 64 + c) * 64 + seg;
#pragma unroll
        for (int j = 0; j < 16; j += 4) {
            f32x4 v4 = *(const f32x4*)(src + j);
            tile[c][seg + j + 0] = v4[0];
            tile[c][seg + j + 1] = v4[1];
            tile[c][seg + j + 2] = v4[2];
            tile[c][seg + j + 3] = v4[3];
        }
    }
    __syncthreads();
    {
        int h = tid >> 2, cs = (tid & 3) << 4;
        unsigned short* dst = wt + (size_t)(arr * 64 + h) * 1024 + ct * 64 + cs;
#pragma unroll
        for (int j = 0; j < 16; ++j) dst[j] = f2bf(tile[cs + j][h]);
    }
}

// ---------------------------------------------------------------------------
// Kernel 2 (v3): kqv projection GEMM, occupancy-fixed.
// BM=32, BK=64, 512 threads (8 waves), grid 512 -> 2 blocks/CU (56 KB LDS),
// 4 waves/SIMD (rounds 1-7 ran 1 wave/SIMD -> BW-starved at 28 us vs 11 floor).
// Wave w: m-frag (w&1), n-frags (w>>1)*3+{0..2}. Same verified staging
// (coalesced f32x4 idx loads, cvt_pk, XOR-swizzled LDS) and epilogue.
// ---------------------------------------------------------------------------
__global__ __launch_bounds__(512, 4) void proj_gemm(const float* __restrict__ idx,
                                                    const unsigned short* __restrict__ wt,
                                                    unsigned short* __restrict__ kw,
                                                    unsigned short* __restrict__ qw,
                                                    unsigned short* __restrict__ vtw) {
    __shared__ unsigned short As[2][32 * 64];    // 8 KB
    __shared__ unsigned short Bs[2][192 * 64];   // 48 KB
    const int tid = threadIdx.x;
    const int lane = tid & 63, w = tid >> 6;
    const int g = lane >> 4, l15 = lane & 15;
    const int m0 = blockIdx.x * 32;
    const int arow = tid >> 4, aseg = tid & 15;   // A: 32 rows x 16 f32x4-segs

    f32x4 acc[3] = {};
    f32x4 areg;
    u16x8 breg[3];

    auto sload = [&](int k0) {
        areg = *(const f32x4*)(idx + (size_t)(m0 + arow) * 1024 + k0 + aseg * 4);
#pragma unroll
        for (int i = 0; i < 3; ++i) {
            int slot = i * 512 + tid, n = slot >> 3, u = slot & 7;
            breg[i] = *(const u16x8*)(wt + (size_t)n * 1024 + k0 + u * 8);
        }
    };
    auto swrite = [&](int buf) {
        unsigned d0, d1;
        cvtpk4(areg[0], areg[1], areg[2], areg[3], d0, d1);
        int au = aseg >> 1, ah = aseg & 1;
        uint2 pk; pk.x = d0; pk.y = d1;
        *(uint2*)&As[buf][arow * 64 + ((au ^ (arow & 7)) * 8) + ah * 4] = pk;
#pragma unroll
        for (int i = 0; i < 3; ++i) {
            int slot = i * 512 + tid, n = slot >> 3, u = slot & 7;
            *(u16x8*)&Bs[buf][n * 64 + ((u ^ (n & 7)) * 8)] = breg[i];
        }
    };

    sload(0);
    swrite(0);
    __syncthreads();

    int cur = 0;
    for (int kt = 0; kt < 16; ++kt) {
        if (kt < 15) sload((kt + 1) * 64);
#pragma unroll
        for (int ks = 0; ks < 2; ++ks) {
            u16x8 a = *(const u16x8*)&As[cur][((w & 1) * 16 + l15) * 64 +
                                              (((ks * 4 + g) ^ (l15 & 7)) * 8)];
#pragma unroll
            for (int nf = 0; nf < 3; ++nf) {
                int n = (w >> 1) * 48 + nf * 16 + l15;
                u16x8 b = *(const u16x8*)&Bs[cur][n * 64 + (((ks * 4 + g) ^ (n & 7)) * 8)];
                acc[nf] = mfma16(a, b, acc[nf]);
            }
        }
        if (kt < 15) swrite(cur ^ 1);
        __syncthreads();
        cur ^= 1;
    }

    // epilogue: D layout col=lane&15, row=g*4+reg
#pragma unroll
    for (int nf = 0; nf < 3; ++nf) {
        int nb = (w >> 1) * 3 + nf;      // 16-col block 0..11
        int arr = nb >> 2;               // 0=k 1=q 2=v
        int nloc = ((nb & 3) << 4) + l15;
        f32x4 ac = acc[nf];
        int row = m0 + (w & 1) * 16 + g * 4;
        if (arr == 2) {
            u16x4 pk = {f2bf(ac[0]), f2bf(ac[1]), f2bf(ac[2]), f2bf(ac[3])};
            *(u16x4*)&vtw[(size_t)nloc * BT_ + row] = pk;   // vT[h][row]
        } else {
            unsigned short* dst = arr ? qw : kw;
            dst[(size_t)(row + 0) * 64 + nloc] = f2bf(ac[0]);
            dst[(size_t)(row + 1) * 64 + nloc] = f2bf(ac[1]);
            dst[(size_t)(row + 2) * 64 + nloc] = f2bf(ac[2]);
            dst[(size_t)(row + 3) * 64 + nloc] = f2bf(ac[3]);
        }
    }
}

// ---------------------------------------------------------------------------
// Kernel 3 (v7): attention partials with LDS-SHARED s-tile staging.
// Block = (b, pair j: t-tiles [128j..+127] & [128(15-j)..+127], s-partial 0..3).
// Wave w owns 16 t-rows of each tile (tA0=128j+16w, tB0=128(15-j)+16w).
// Block loops s-tiles st = part, part+4, ... < 2(16-j): stage q[64][64] +
// vT[64][64] into LDS ONCE (shared by all 8 waves; kills the 33x private L2
// re-read of rounds 2-7), double-buffered, issue-early/write-late. Per-unit
// compute = verified v5/v6 path (S^T mfma, static-max softmax, p transpose,
// PV) with per-wave dA/dB activity masks. Partial (O f32, l) -> workspace.
// 34 cost-units per pair => ~8.5/partial, balanced. grid 256 x 512.
// ---------------------------------------------------------------------------
__global__ __launch_bounds__(512, 2) void attn_part(const unsigned short* __restrict__ kw,
                                                    const unsigned short* __restrict__ qw,
                                                    const unsigned short* __restrict__ vtw,
                                                    float* __restrict__ Opart,
                                                    float* __restrict__ lpart) {
    __shared__ unsigned short q_s[2][64 * 64];   // 16 KB
    __shared__ unsigned short v_s[2][64 * 64];   // 16 KB
    __shared__ unsigned short p_s[8 * 32 * 64];  // 32 KB (per-wave P transpose)
    const int tid = threadIdx.x;
    const int w = tid >> 6, lane = tid & 63;
    const int g = lane >> 4, l15 = lane & 15;
    const int bid = blockIdx.x;
    const int b = bid & 7;                  // XCD-local batch
    const int rem = bid >> 3;
    const int j = rem & 7;                  // pair index 0..7
    const int part = rem >> 3;              // s-partial 0..3
    const size_t base = (size_t)b * T_;
    const int tA0 = 128 * j + 16 * w;
    const int tB0 = 128 * (15 - j) + 16 * w;
    const int nS = 2 * (16 - j);            // s-tiles covering tile B's range
    const int cnt = (nS - part + 3) >> 2;   // tiles for this partial (>=4)
    unsigned short* p_my = p_s + w * 2048;
    const float SCL = 0.125f * 1.44269504f;
    const float MOFF = 16.0f;
    const int sr = tid >> 3, su = tid & 7;  // staging: 64 rows x 8 units

    // k fragments (tf=0 -> tile A rows, tf=1 -> tile B rows)
    u16x8 kf[2][2];
#pragma unroll
    for (int tf = 0; tf < 2; ++tf) {
        const unsigned short* kr = kw + (size_t)(base + (tf ? tB0 : tA0) + l15) * 64;
        kf[tf][0] = *(const u16x8*)(kr + g * 8);
        kf[tf][1] = *(const u16x8*)(kr + 32 + g * 8);
    }

    f32x4 o[4][2] = {};
    float l_lane[2] = {0.f, 0.f};

    u16x8 tq, tv;
    auto sload = [&](int st) {
        int s0 = st << 6;
        tq = *(const u16x8*)(qw + (size_t)(base + s0 + sr) * 64 + su * 8);
        tv = *(const u16x8*)(vtw + (size_t)sr * BT_ + base + s0 + su * 8);
    };
    auto swrite = [&](int buf) {
        *(u16x8*)&q_s[buf][sr * 64 + ((su ^ (sr & 7)) * 8)] = tq;
        *(u16x8*)&v_s[buf][sr * 64 + ((su ^ (sr & 7)) * 8)] = tv;
    };

    sload(part);
    swrite(0);
    __syncthreads();

    for (int i = 0; i < cnt; ++i) {
        const int st = part + 4 * i;
        const int s0 = st << 6;
        const int buf = i & 1;
        if (i + 1 < cnt) sload(part + 4 * (i + 1));   // issue-early
        const bool dA = (s0 <= tA0 + 15);
        const bool dB = (s0 <= tB0 + 15);

        // ---- a-frags from shared q tile (used by both tf) ----
        u16x8 a[2][4];
#pragma unroll
        for (int ks = 0; ks < 2; ++ks)
#pragma unroll
            for (int sf = 0; sf < 4; ++sf)
                a[ks][sf] = *(const u16x8*)&q_s[buf][(sf * 16 + l15) * 64 +
                                                     (((ks * 4 + g) ^ (l15 & 7)) * 8)];

        // ---- QK^T ----
        f32x4 s_[4][2] = {};
        __builtin_amdgcn_s_setprio(1);
        if (dB) {
#pragma unroll
            for (int ks = 0; ks < 2; ++ks)
#pragma unroll
                for (int sf = 0; sf < 4; ++sf)
                    s_[sf][1] = mfma16(a[ks][sf], kf[1][ks], s_[sf][1]);
        }
        if (dA) {
#pragma unroll
            for (int ks = 0; ks < 2; ++ks)
#pragma unroll
                for (int sf = 0; sf < 4; ++sf)
                    s_[sf][0] = mfma16(a[ks][sf], kf[0][ks], s_[sf][0]);
        }
        __builtin_amdgcn_s_setprio(0);

        // ---- static-max softmax + p pack (verified v5/v6 path) ----
#pragma unroll
        for (int tf_ = 1; tf_ >= 0; --tf_) {
            if (tf_ ? !dB : !dA) continue;
            const int tbase_ = tf_ ? tB0 : tA0;
            float pv[4][4];
#pragma unroll
            for (int sf = 0; sf < 4; ++sf)
#pragma unroll
                for (int r = 0; r < 4; ++r)
                    pv[sf][r] = exp2f(fmaf(s_[sf][tf_][r], SCL, -MOFF));
            if (s0 + 63 > tbase_) {
                const int t_ = tbase_ + l15;
#pragma unroll
                for (int sf = 0; sf < 4; ++sf)
#pragma unroll
                    for (int r = 0; r < 4; ++r) {
                        int sg = s0 + sf * 16 + g * 4 + r;
                        if (sg > t_) pv[sf][r] = 0.f;
                    }
            }
            float lacc = 0.f;
#pragma unroll
            for (int sf = 0; sf < 4; ++sf)
                lacc += (pv[sf][0] + pv[sf][1]) + (pv[sf][2] + pv[sf][3]);
            l_lane[tf_] += lacc;
            const int trow = tf_ * 16 + l15;
#pragma unroll
            for (int sf = 0; sf < 4; ++sf) {
                unsigned r0, r1;
                cvtpk4(pv[sf][0], pv[sf][1], pv[sf][2], pv[sf][3], r0, r1);
                int u16i = (sf * 2 + (g >> 1)) ^ (l15 & 7);
                uint2 pk; pk.x = r0; pk.y = r1;
                *(uint2*)&p_my[trow * 64 + u16i * 8 + (g & 1) * 4] = pk;
            }
        }

        // ---- PV from shared vT tile ----
        u16x8 vf[2][4];
#pragma unroll
        for (int ks = 0; ks < 2; ++ks)
#pragma unroll
            for (int mf = 0; mf < 4; ++mf)
                vf[ks][mf] = *(const u16x8*)&v_s[buf][(mf * 16 + l15) * 64 +
                                                      (((ks * 4 + g) ^ (l15 & 7)) * 8)];
        __builtin_amdgcn_s_setprio(1);
#pragma unroll
        for (int ks = 0; ks < 2; ++ks) {
            if (dB) {
                u16x8 bp1 = *(const u16x8*)&p_my[(16 + l15) * 64 +
                                                 (((ks * 4 + g) ^ (l15 & 7)) * 8)];
#pragma unroll
                for (int mf = 0; mf < 4; ++mf)
                    o[mf][1] = mfma16(vf[ks][mf], bp1, o[mf][1]);
            }
            if (dA) {
                u16x8 bp0 = *(const u16x8*)&p_my[l15 * 64 +
                                                 (((ks * 4 + g) ^ (l15 & 7)) * 8)];
#pragma unroll
                for (int mf = 0; mf < 4; ++mf)
                    o[mf][0] = mfma16(vf[ks][mf], bp0, o[mf][0]);
            }
        }
        __builtin_amdgcn_s_setprio(0);

        if (i + 1 < cnt) swrite(buf ^ 1);   // write-late into other buffer
        __syncthreads();
    }

    // ---- store partials: O^T lanes col=t, rows h contiguous ----
#pragma unroll
    for (int tf = 0; tf < 2; ++tf) {
        float ls = l_lane[tf];
        ls += __shfl_xor(ls, 16);
        ls += __shfl_xor(ls, 32);
        int rl = tf * 128 + w * 16 + l15;     // row_local 0..255
        if (g == 0) lpart[(size_t)bid * 256 + rl] = ls;
#pragma unroll
        for (int mf = 0; mf < 4; ++mf)
            *(f32x4*)&Opart[(size_t)bid * 16384 + (size_t)rl * 64 + mf * 16 + g * 4] = o[mf][tf];
    }
}

// ---------------------------------------------------------------------------
// Kernel 4: combine 4 s-partials: out = sum(O_p) / sum(l_p).
// grid 1024 x 256; thread -> (row, 4 h-cols).
// ---------------------------------------------------------------------------
__global__ __launch_bounds__(256) void attn_comb(const float* __restrict__ Opart,
                                                 const float* __restrict__ lpart,
                                                 float* __restrict__ out) {
    int gt = blockIdx.x * 256 + threadIdx.x;
    int row = gt >> 4;                // 0..16383 = b*2048 + t
    int h0 = (gt & 15) << 2;
    int b = row >> 11, t = row & 2047;
    int ti = t >> 7, rit = t & 127;
    int j = (ti < 8) ? ti : (15 - ti);
    int tf = (ti < 8) ? 0 : 1;
    int rl = tf * 128 + rit;
    f32x4 acc = {};
    float L = 0.f;
#pragma unroll
    for (int part = 0; part < 4; ++part) {
        int pb = b + 8 * j + 64 * part;
        acc += *(const f32x4*)&Opart[(size_t)pb * 16384 + (size_t)rl * 64 + h0];
        L += lpart[(size_t)pb * 256 + rl];
    }
    float inv = 1.f / L;
    *(f32x4*)&out[(size_t)row * 64 + h0] = acc * inv;
}

// ---------------------------------------------------------------------------
extern "C" void kernel_launch(void* const* d_in, const int* in_sizes, int n_in,
                              void* d_out, int out_size, void* d_ws, size_t ws_size,
                              hipStream_t stream) {
    const float* idx = (const float*)d_in[0];
    const float* Wk = (const float*)d_in[1];
    const float* Wq = (const float*)d_in[2];
    const float* Wv = (const float*)d_in[3];
    float* out = (float*)d_out;

    // ws: bf16 region [wt | kw | qw | vtw] (6.7 MB), then f32 partials at 8 MB
    unsigned short* wt = (unsigned short*)d_ws;
    unsigned short* kw = wt + 192 * 1024;
    unsigned short* qw = kw + (size_t)BT_ * 64;
    unsigned short* vtw = qw + (size_t)BT_ * 64;
    float* Opart = (float*)((char*)d_ws + (8u << 20));      // 256*16384 f32 = 16.78 MB
    float* lpart = Opart + (size_t)256 * 16384;             // 256*256 f32

    wprep<<<48, 256, 0, stream>>>(Wk, Wq, Wv, wt);
    proj_gemm<<<512, 512, 0, stream>>>(idx, wt, kw, qw, vtw);
    attn_part<<<256, 512, 0, stream>>>(kw, qw, vtw, Opart, lpart);
    attn_comb<<<1024, 256, 0, stream>>>(Opart, lpart, out);
}